// Round 1
// baseline (2799.300 us; speedup 1.0000x reference)
//
#include <hip/hip_runtime.h>
#include <cstdint>
#include <cstddef>

#define LQ     2048
#define DM     256
#define NKEY   16384
#define NLVL   4
#define LVLN   4096
#define NCHUNK 16
#define CHUNKN 1024
#define BM     64
#define BN     128
#define KB     32
#define MGRPS  (LQ / BM)    // 32
#define CLIPMX 3969         // (h-1)*(w-1)
#define QB     8

// ---------- branchless sorted-insert into top-4 (desc value) ----------
// strict: later-inserted equal values lose (valid when idx inserted ascending)
__device__ __forceinline__ void ins_strict(float v, int ix, float tv[4], int ti[4]) {
  bool c0 = v > tv[0], c1 = v > tv[1], c2 = v > tv[2], c3 = v > tv[3];
  tv[3] = c2 ? tv[2] : (c3 ? v : tv[3]);
  ti[3] = c2 ? ti[2] : (c3 ? ix : ti[3]);
  tv[2] = c1 ? tv[1] : (c2 ? v : tv[2]);
  ti[2] = c1 ? ti[1] : (c2 ? ix : ti[2]);
  tv[1] = c0 ? tv[0] : (c1 ? v : tv[1]);
  ti[1] = c0 ? ti[0] : (c1 ? ix : ti[1]);
  tv[0] = c0 ? v : tv[0];
  ti[0] = c0 ? ix : ti[0];
}

// tie-break: equal value -> smaller index wins (numpy/jax top_k semantics)
__device__ __forceinline__ void ins_tb(float v, int ix, float tv[4], int ti[4]) {
  bool c0 = (v > tv[0]) || (v == tv[0] && ix < ti[0]);
  bool c1 = (v > tv[1]) || (v == tv[1] && ix < ti[1]);
  bool c2 = (v > tv[2]) || (v == tv[2] && ix < ti[2]);
  bool c3 = (v > tv[3]) || (v == tv[3] && ix < ti[3]);
  tv[3] = c2 ? tv[2] : (c3 ? v : tv[3]);
  ti[3] = c2 ? ti[2] : (c3 ? ix : ti[3]);
  tv[2] = c1 ? tv[1] : (c2 ? v : tv[2]);
  ti[2] = c1 ? ti[1] : (c2 ? ix : ti[2]);
  tv[1] = c0 ? tv[0] : (c1 ? v : tv[1]);
  ti[1] = c0 ? ti[0] : (c1 ? ix : ti[1]);
  tv[0] = c0 ? v : tv[0];
  ti[0] = c0 ? ix : ti[0];
}

// ---------- kernel A: fp32 GEMM (Q·K^T) fused with per-chunk top-4 ----------
// grid (MGRPS, NCHUNK), block 256. BM=64 queries x CHUNKN=1024 keys per WG.
__global__ __launch_bounds__(256, 2) void corr_topk(
    const float* __restrict__ Qm, const float* __restrict__ Km,
    float* __restrict__ cv, int* __restrict__ ci)
{
  const int tid  = threadIdx.x;
  const int mgrp = blockIdx.x;
  const int chnk = blockIdx.y;
  const int ty = tid >> 4, tx = tid & 15;

  __shared__ float As[2][KB][BM + 4];   // stride 68 floats (16B-aligned rows)
  __shared__ float Bs[2][KB][BN + 4];   // stride 132 floats

  float tv[4][4];
  int   ti[4][4];
#pragma unroll
  for (int i = 0; i < 4; ++i)
#pragma unroll
    for (int s = 0; s < 4; ++s) { tv[i][s] = -3.4e38f; ti[i][s] = 0x7fffffff; }

  const float* Aslab = Qm + (size_t)mgrp * BM * DM;
  const float* Bslab = Km + (size_t)chnk * CHUNKN * DM;

#pragma unroll 1
  for (int nt = 0; nt < CHUNKN / BN; ++nt) {
    const float* Bt = Bslab + (size_t)nt * BN * DM;
    float acc[4][8];
#pragma unroll
    for (int i = 0; i < 4; ++i)
#pragma unroll
      for (int j = 0; j < 8; ++j) acc[i][j] = 0.f;

    float4 aR[2], bR[4];
    // prologue: load k-chunk 0 -> regs -> LDS buf 0
#pragma unroll
    for (int i = 0; i < 2; ++i) {
      const int f = i * 256 + tid, r = f >> 3, s = f & 7;
      aR[i] = *(const float4*)(Aslab + (size_t)r * DM + s * 4);
    }
#pragma unroll
    for (int i = 0; i < 4; ++i) {
      const int f = i * 256 + tid, r = f >> 3, s = f & 7;
      bR[i] = *(const float4*)(Bt + (size_t)r * DM + s * 4);
    }
#pragma unroll
    for (int i = 0; i < 2; ++i) {
      const int f = i * 256 + tid, r = f >> 3, s = f & 7;
      As[0][s*4+0][r] = aR[i].x; As[0][s*4+1][r] = aR[i].y;
      As[0][s*4+2][r] = aR[i].z; As[0][s*4+3][r] = aR[i].w;
    }
#pragma unroll
    for (int i = 0; i < 4; ++i) {
      const int f = i * 256 + tid, r = f >> 3, s = f & 7;
      Bs[0][s*4+0][r] = bR[i].x; Bs[0][s*4+1][r] = bR[i].y;
      Bs[0][s*4+2][r] = bR[i].z; Bs[0][s*4+3][r] = bR[i].w;
    }

#pragma unroll 1
    for (int kc = 0; kc < DM / KB; ++kc) {
      __syncthreads();
      if (kc < DM / KB - 1) {
        const int ko = (kc + 1) * KB;
#pragma unroll
        for (int i = 0; i < 2; ++i) {
          const int f = i * 256 + tid, r = f >> 3, s = f & 7;
          aR[i] = *(const float4*)(Aslab + (size_t)r * DM + ko + s * 4);
        }
#pragma unroll
        for (int i = 0; i < 4; ++i) {
          const int f = i * 256 + tid, r = f >> 3, s = f & 7;
          bR[i] = *(const float4*)(Bt + (size_t)r * DM + ko + s * 4);
        }
      }
      const int buf = kc & 1;
#pragma unroll
      for (int k = 0; k < KB; ++k) {
        float a[4], b[8];
        *(float4*)&a[0] = *(const float4*)&As[buf][k][ty * 4];
        *(float4*)&b[0] = *(const float4*)&Bs[buf][k][tx * 8];
        *(float4*)&b[4] = *(const float4*)&Bs[buf][k][tx * 8 + 4];
#pragma unroll
        for (int i = 0; i < 4; ++i)
#pragma unroll
          for (int j = 0; j < 8; ++j)
            acc[i][j] = fmaf(a[i], b[j], acc[i][j]);
      }
      if (kc < DM / KB - 1) {
        const int nb = buf ^ 1;
#pragma unroll
        for (int i = 0; i < 2; ++i) {
          const int f = i * 256 + tid, r = f >> 3, s = f & 7;
          As[nb][s*4+0][r] = aR[i].x; As[nb][s*4+1][r] = aR[i].y;
          As[nb][s*4+2][r] = aR[i].z; As[nb][s*4+3][r] = aR[i].w;
        }
#pragma unroll
        for (int i = 0; i < 4; ++i) {
          const int f = i * 256 + tid, r = f >> 3, s = f & 7;
          Bs[nb][s*4+0][r] = bR[i].x; Bs[nb][s*4+1][r] = bR[i].y;
          Bs[nb][s*4+2][r] = bR[i].z; Bs[nb][s*4+3][r] = bR[i].w;
        }
      }
    }

    // fold this 64x128 tile into per-thread running top-4 (idx ascending per thread)
    const int colbase = chnk * CHUNKN + nt * BN + tx * 8;
#pragma unroll
    for (int i = 0; i < 4; ++i)
#pragma unroll
      for (int j = 0; j < 8; ++j)
        ins_strict(acc[i][j], colbase + j, tv[i], ti[i]);
  }

  // merge 16 per-thread lists per query row via LDS (reuse staging buffers)
  __syncthreads();
  float* mv = (float*)(void*)&As[0][0][0];  // 64*16*4 = 4096 floats <= 4352
  int*   mi = (int*)(void*)&Bs[0][0][0];    // <= 8448
#pragma unroll
  for (int i = 0; i < 4; ++i)
#pragma unroll
    for (int s = 0; s < 4; ++s) {
      const int row = ty * 4 + i;
      mv[(row * 16 + tx) * 4 + s] = tv[i][s];
      mi[(row * 16 + tx) * 4 + s] = ti[i][s];
    }
  __syncthreads();
  if (tid < BM) {
    float bv[4] = {-3.4e38f, -3.4e38f, -3.4e38f, -3.4e38f};
    int   bi[4] = {0x7fffffff, 0x7fffffff, 0x7fffffff, 0x7fffffff};
#pragma unroll 1
    for (int c = 0; c < 16; ++c)
#pragma unroll
      for (int s = 0; s < 4; ++s)
        ins_tb(mv[(tid * 16 + c) * 4 + s], mi[(tid * 16 + c) * 4 + s], bv, bi);
    const int q = mgrp * BM + tid;
#pragma unroll
    for (int s = 0; s < 4; ++s) {
      cv[((size_t)q * NCHUNK + chnk) * 4 + s] = bv[s];
      ci[((size_t)q * NCHUNK + chnk) * 4 + s] = bi[s];
    }
  }
}

// ---------- kernel B: merge 4 chunks/level -> final top-4, emit sampling_locations ----------
__global__ void merge_loc(const float* __restrict__ cv, const int* __restrict__ ci,
                          int* __restrict__ tix, float* __restrict__ sloc)
{
  const int g = blockIdx.x * 256 + threadIdx.x;
  if (g >= LQ * NLVL) return;
  const int q = g >> 2, l = g & 3;
  float bv[4] = {-3.4e38f, -3.4e38f, -3.4e38f, -3.4e38f};
  int   bi[4] = {0x7fffffff, 0x7fffffff, 0x7fffffff, 0x7fffffff};
#pragma unroll
  for (int c = 0; c < 4; ++c) {
    const int ch = l * 4 + c;
#pragma unroll
    for (int s = 0; s < 4; ++s)
      ins_tb(cv[((size_t)q * NCHUNK + ch) * 4 + s],
             ci[((size_t)q * NCHUNK + ch) * 4 + s], bv, bi);
  }
  const int nei[9] = {-65, -64, -63, -1, 0, 1, 63, 64, 65};
  float* sl = sloc + (size_t)g * 72;   // 36 points * 2
#pragma unroll
  for (int p = 0; p < 4; ++p) {
    const int li = bi[p] - l * LVLN;   // level-local index in [0,4096)
    tix[g * 4 + p] = li;
#pragma unroll
    for (int n9 = 0; n9 < 9; ++n9) {
      int r = li + nei[n9];
      r = r < 0 ? 0 : (r > CLIPMX ? CLIPMX : r);
      // j = n9*4 + p ; loc = (off_w/64, off_h/64), exact
      sl[(n9 * 4 + p) * 2 + 0] = (float)(r >> 6) * 0.015625f;
      sl[(n9 * 4 + p) * 2 + 1] = (float)(r & 63) * 0.015625f;
    }
  }
}

// ---------- kernel C: gather + accumulate pre-projection output ----------
// one block per query, one thread per channel
__global__ void samp_acc(const float* __restrict__ V, const int* __restrict__ tix,
                         float* __restrict__ pre)
{
  const int q = blockIdx.x, d = threadIdx.x;
  const int nei[9] = {-65, -64, -63, -1, 0, 1, 63, 64, 65};
  float acc = 0.f;
#pragma unroll 1
  for (int l = 0; l < NLVL; ++l) {
    const float* Vb = V + (size_t)l * LVLN * DM;
    for (int p = 0; p < 4; ++p) {
      const int p0 = tix[(q * NLVL + l) * 4 + p];
      const int xw = p0 >> 6, yh = p0 & 63;
      if (p0 >= 65 && p0 <= 3904 && yh >= 1 && yh <= 62) {
        // fast path: 4x4 window, weights [1,2,2,1] x [1,2,2,1] (sums to 36 taps)
#pragma unroll
        for (int a = 0; a < 4; ++a) {
          const int y = yh - 2 + a;
          if (y < 0) continue;
          const float wa = (a == 1 || a == 2) ? 2.f : 1.f;
#pragma unroll
          for (int bb = 0; bb < 4; ++bb) {
            const int x = xw - 2 + bb;
            if (x < 0) continue;
            const float wb = (bb == 1 || bb == 2) ? 2.f : 1.f;
            acc = fmaf(wa * wb, Vb[(size_t)(y * 64 + x) * DM + d], acc);
          }
        }
      } else {
        // exact per-neighbor path with clip + border masks
#pragma unroll
        for (int n9 = 0; n9 < 9; ++n9) {
          int r = p0 + nei[n9];
          r = r < 0 ? 0 : (r > CLIPMX ? CLIPMX : r);
          const int x = r >> 6, y = r & 63;
          const int b0 = y * 64 + x;
          float s = Vb[(size_t)b0 * DM + d];
          if (x > 0) s += Vb[(size_t)(b0 - 1) * DM + d];
          if (y > 0) {
            s += Vb[(size_t)(b0 - 64) * DM + d];
            if (x > 0) s += Vb[(size_t)(b0 - 65) * DM + d];
          }
          acc += s;
        }
      }
    }
  }
  pre[(size_t)q * DM + d] = acc * (0.25f / 144.f);
}

// ---------- kernel D0: transpose out_w (256x256) ----------
__global__ void transp_w(const float* __restrict__ W, float* __restrict__ Wt)
{
  __shared__ float t[32][33];
  const int bx = blockIdx.x * 32, by = blockIdx.y * 32;
  t[threadIdx.y][threadIdx.x] = W[(size_t)(by + threadIdx.y) * DM + bx + threadIdx.x];
  __syncthreads();
  Wt[(size_t)(bx + threadIdx.y) * DM + by + threadIdx.x] = t[threadIdx.x][threadIdx.y];
}

// ---------- kernel D: out = pre @ W^T + b ----------
__global__ __launch_bounds__(256) void proj_out(
    const float* __restrict__ pre, const float* __restrict__ Wt,
    const float* __restrict__ bias, float* __restrict__ outp)
{
  const int q0 = blockIdx.x * QB;
  const int e = threadIdx.x;
  float acc[QB];
#pragma unroll
  for (int i = 0; i < QB; ++i) acc[i] = 0.f;
#pragma unroll 4
  for (int d = 0; d < DM; ++d) {
    const float w = Wt[(size_t)d * DM + e];   // coalesced, L2-hot
#pragma unroll
    for (int qq = 0; qq < QB; ++qq)
      acc[qq] = fmaf(pre[(size_t)(q0 + qq) * DM + d], w, acc[qq]);  // uniform -> scalar loads
  }
  const float be = bias[e];
#pragma unroll
  for (int qq = 0; qq < QB; ++qq)
    outp[(size_t)(q0 + qq) * DM + e] = acc[qq] + be;
}

extern "C" void kernel_launch(void* const* d_in, const int* in_sizes, int n_in,
                              void* d_out, int out_size, void* d_ws, size_t ws_size,
                              hipStream_t stream)
{
  const float* Q    = (const float*)d_in[0];   // [2048][256]
  const float* V    = (const float*)d_in[2];   // [16384][256]
  const float* W    = (const float*)d_in[5];   // [256][256]
  const float* bias = (const float*)d_in[6];   // [256]

  float* outp = (float*)d_out;                 // [2048][256]
  float* sloc = outp + (size_t)LQ * DM;        // [2048][4][36][2]

  char* ws = (char*)d_ws;
  float* cv  = (float*)(ws);                   // [2048][16][4]  512KB
  int*   ci  = (int*)  (ws + 0x80000);         // [2048][16][4]  512KB
  int*   tix = (int*)  (ws + 0x100000);        // [2048][4][4]   128KB
  float* pre = (float*)(ws + 0x120000);        // [2048][256]    2MB
  float* Wt  = (float*)(ws + 0x320000);        // [256][256]     256KB

  corr_topk<<<dim3(MGRPS, NCHUNK), 256, 0, stream>>>(Q, V, cv, ci);
  merge_loc<<<dim3((LQ * NLVL + 255) / 256), 256, 0, stream>>>(cv, ci, tix, sloc);
  samp_acc<<<dim3(LQ), 256, 0, stream>>>(V, tix, pre);
  transp_w<<<dim3(8, 8), dim3(32, 32), 0, stream>>>(W, Wt);
  proj_out<<<dim3(LQ / QB), 256, 0, stream>>>(pre, Wt, bias, outp);
}

// Round 2
// 2364.801 us; speedup vs baseline: 1.1837x; 1.1837x over previous
//
#include <hip/hip_runtime.h>
#include <cstdint>
#include <cstddef>

#define LQ     2048
#define DM     256
#define NKEY   16384
#define NLVL   4
#define LVLN   4096
#define NCHUNK 16
#define CHUNKN 1024
#define BM     64
#define BN     128
#define KB     32
#define MGRPS  (LQ / BM)    // 32
#define CLIPMX 3969         // (h-1)*(w-1)
#define QB     8

// ---------- branchless sorted-insert into top-4, register-only (no arrays) ----------
// strict: later-inserted equal values lose (valid when idx inserted ascending)
__device__ __forceinline__ void ins4(float v, int ix, float4& tv, int4& ti) {
  bool c0 = v > tv.x, c1 = v > tv.y, c2 = v > tv.z, c3 = v > tv.w;
  tv.w = c2 ? tv.z : (c3 ? v : tv.w);
  ti.w = c2 ? ti.z : (c3 ? ix : ti.w);
  tv.z = c1 ? tv.y : (c2 ? v : tv.z);
  ti.z = c1 ? ti.y : (c2 ? ix : ti.z);
  tv.y = c0 ? tv.x : (c1 ? v : tv.y);
  ti.y = c0 ? ti.x : (c1 ? ix : ti.y);
  tv.x = c0 ? v : tv.x;
  ti.x = c0 ? ix : ti.x;
}

// tie-break: equal value -> smaller index wins (numpy/jax top_k semantics)
__device__ __forceinline__ void ins4_tb(float v, int ix, float4& tv, int4& ti) {
  bool c0 = (v > tv.x) || (v == tv.x && ix < ti.x);
  bool c1 = (v > tv.y) || (v == tv.y && ix < ti.y);
  bool c2 = (v > tv.z) || (v == tv.z && ix < ti.z);
  bool c3 = (v > tv.w) || (v == tv.w && ix < ti.w);
  tv.w = c2 ? tv.z : (c3 ? v : tv.w);
  ti.w = c2 ? ti.z : (c3 ? ix : ti.w);
  tv.z = c1 ? tv.y : (c2 ? v : tv.z);
  ti.z = c1 ? ti.y : (c2 ? ix : ti.z);
  tv.y = c0 ? tv.x : (c1 ? v : tv.y);
  ti.y = c0 ? ti.x : (c1 ? ix : ti.y);
  tv.x = c0 ? v : tv.x;
  ti.x = c0 ? ix : ti.x;
}

// array-based tie-break insert (tiny merge_loc kernel only)
__device__ __forceinline__ void ins_tb(float v, int ix, float tv[4], int ti[4]) {
  bool c0 = (v > tv[0]) || (v == tv[0] && ix < ti[0]);
  bool c1 = (v > tv[1]) || (v == tv[1] && ix < ti[1]);
  bool c2 = (v > tv[2]) || (v == tv[2] && ix < ti[2]);
  bool c3 = (v > tv[3]) || (v == tv[3] && ix < ti[3]);
  tv[3] = c2 ? tv[2] : (c3 ? v : tv[3]);
  ti[3] = c2 ? ti[2] : (c3 ? ix : ti[3]);
  tv[2] = c1 ? tv[1] : (c2 ? v : tv[2]);
  ti[2] = c1 ? ti[1] : (c2 ? ix : ti[2]);
  tv[1] = c0 ? tv[0] : (c1 ? v : tv[1]);
  ti[1] = c0 ? ti[0] : (c1 ? ix : ti[1]);
  tv[0] = c0 ? v : tv[0];
  ti[0] = c0 ? ix : ti[0];
}

#define FMA4(accv, s, bv)                  \
  accv.x = fmaf(s, bv.x, accv.x);          \
  accv.y = fmaf(s, bv.y, accv.y);          \
  accv.z = fmaf(s, bv.z, accv.z);          \
  accv.w = fmaf(s, bv.w, accv.w);

// ---------- kernel A: fp32 GEMM (Q·K^T) fused with per-chunk top-4 ----------
// grid (MGRPS, NCHUNK), block 256. BM=64 queries x CHUNKN=1024 keys per WG.
__global__ __launch_bounds__(256, 2) void corr_topk(
    const float* __restrict__ Qm, const float* __restrict__ Km,
    float* __restrict__ cv, int* __restrict__ ci)
{
  const int tid  = threadIdx.x;
  const int mgrp = blockIdx.x;
  const int chnk = blockIdx.y;
  const int ty = tid >> 4, tx = tid & 15;
  const int r0 = tid >> 3, s0 = tid & 7;     // staging: row base / 16B-column slot

  __shared__ __align__(16) float As[2][KB][BM + 4];   // stride 68 floats
  __shared__ __align__(16) float Bs[2][KB][BN + 4];   // stride 132 floats

  const float4 NEGI = {-3.4e38f, -3.4e38f, -3.4e38f, -3.4e38f};
  const int4   MAXI = {0x7fffffff, 0x7fffffff, 0x7fffffff, 0x7fffffff};
  float4 tv0 = NEGI, tv1 = NEGI, tv2 = NEGI, tv3 = NEGI;
  int4   ti0 = MAXI, ti1 = MAXI, ti2 = MAXI, ti3 = MAXI;

  const float* Aslab = Qm + (size_t)mgrp * BM * DM;
  const float* Bslab = Km + (size_t)chnk * CHUNKN * DM;

#pragma unroll 1
  for (int nt = 0; nt < CHUNKN / BN; ++nt) {
    const float* Bt = Bslab + (size_t)nt * BN * DM;

    float4 c0l = {0,0,0,0}, c0h = {0,0,0,0};
    float4 c1l = {0,0,0,0}, c1h = {0,0,0,0};
    float4 c2l = {0,0,0,0}, c2h = {0,0,0,0};
    float4 c3l = {0,0,0,0}, c3h = {0,0,0,0};

    float4 aR0, aR1, bR0, bR1, bR2, bR3;

#define GLOAD(ko)                                                          \
    aR0 = *(const float4*)(Aslab + (size_t)(r0)      * DM + (ko) + s0*4);  \
    aR1 = *(const float4*)(Aslab + (size_t)(r0 + 32) * DM + (ko) + s0*4);  \
    bR0 = *(const float4*)(Bt    + (size_t)(r0)      * DM + (ko) + s0*4);  \
    bR1 = *(const float4*)(Bt    + (size_t)(r0 + 32) * DM + (ko) + s0*4);  \
    bR2 = *(const float4*)(Bt    + (size_t)(r0 + 64) * DM + (ko) + s0*4);  \
    bR3 = *(const float4*)(Bt    + (size_t)(r0 + 96) * DM + (ko) + s0*4);

#define LSTORE(nb)                                                                   \
    As[nb][s0*4+0][r0]    = aR0.x; As[nb][s0*4+1][r0]    = aR0.y;                    \
    As[nb][s0*4+2][r0]    = aR0.z; As[nb][s0*4+3][r0]    = aR0.w;                    \
    As[nb][s0*4+0][r0+32] = aR1.x; As[nb][s0*4+1][r0+32] = aR1.y;                    \
    As[nb][s0*4+2][r0+32] = aR1.z; As[nb][s0*4+3][r0+32] = aR1.w;                    \
    Bs[nb][s0*4+0][r0]    = bR0.x; Bs[nb][s0*4+1][r0]    = bR0.y;                    \
    Bs[nb][s0*4+2][r0]    = bR0.z; Bs[nb][s0*4+3][r0]    = bR0.w;                    \
    Bs[nb][s0*4+0][r0+32] = bR1.x; Bs[nb][s0*4+1][r0+32] = bR1.y;                    \
    Bs[nb][s0*4+2][r0+32] = bR1.z; Bs[nb][s0*4+3][r0+32] = bR1.w;                    \
    Bs[nb][s0*4+0][r0+64] = bR2.x; Bs[nb][s0*4+1][r0+64] = bR2.y;                    \
    Bs[nb][s0*4+2][r0+64] = bR2.z; Bs[nb][s0*4+3][r0+64] = bR2.w;                    \
    Bs[nb][s0*4+0][r0+96] = bR3.x; Bs[nb][s0*4+1][r0+96] = bR3.y;                    \
    Bs[nb][s0*4+2][r0+96] = bR3.z; Bs[nb][s0*4+3][r0+96] = bR3.w;

    GLOAD(0)
    LSTORE(0)

#pragma unroll 1
    for (int kc = 0; kc < DM / KB; ++kc) {
      __syncthreads();
      if (kc < DM / KB - 1) {
        GLOAD((kc + 1) * KB)
      }
      const int buf = kc & 1;
#pragma unroll
      for (int k = 0; k < KB; ++k) {
        const float4 av = *(const float4*)&As[buf][k][ty * 4];
        const float4 b0 = *(const float4*)&Bs[buf][k][tx * 4];
        const float4 b1 = *(const float4*)&Bs[buf][k][64 + tx * 4];
        FMA4(c0l, av.x, b0) FMA4(c0h, av.x, b1)
        FMA4(c1l, av.y, b0) FMA4(c1h, av.y, b1)
        FMA4(c2l, av.z, b0) FMA4(c2h, av.z, b1)
        FMA4(c3l, av.w, b0) FMA4(c3h, av.w, b1)
      }
      if (kc < DM / KB - 1) {
        const int nb = (kc & 1) ^ 1;
        LSTORE(nb)
      }
    }

    // fold this 64x128 tile into running top-4 (idx strictly ascending per thread)
    const int base = chnk * CHUNKN + nt * BN + tx * 4;
    ins4(c0l.x, base + 0, tv0, ti0); ins4(c0l.y, base + 1, tv0, ti0);
    ins4(c0l.z, base + 2, tv0, ti0); ins4(c0l.w, base + 3, tv0, ti0);
    ins4(c0h.x, base + 64, tv0, ti0); ins4(c0h.y, base + 65, tv0, ti0);
    ins4(c0h.z, base + 66, tv0, ti0); ins4(c0h.w, base + 67, tv0, ti0);

    ins4(c1l.x, base + 0, tv1, ti1); ins4(c1l.y, base + 1, tv1, ti1);
    ins4(c1l.z, base + 2, tv1, ti1); ins4(c1l.w, base + 3, tv1, ti1);
    ins4(c1h.x, base + 64, tv1, ti1); ins4(c1h.y, base + 65, tv1, ti1);
    ins4(c1h.z, base + 66, tv1, ti1); ins4(c1h.w, base + 67, tv1, ti1);

    ins4(c2l.x, base + 0, tv2, ti2); ins4(c2l.y, base + 1, tv2, ti2);
    ins4(c2l.z, base + 2, tv2, ti2); ins4(c2l.w, base + 3, tv2, ti2);
    ins4(c2h.x, base + 64, tv2, ti2); ins4(c2h.y, base + 65, tv2, ti2);
    ins4(c2h.z, base + 66, tv2, ti2); ins4(c2h.w, base + 67, tv2, ti2);

    ins4(c3l.x, base + 0, tv3, ti3); ins4(c3l.y, base + 1, tv3, ti3);
    ins4(c3l.z, base + 2, tv3, ti3); ins4(c3l.w, base + 3, tv3, ti3);
    ins4(c3h.x, base + 64, tv3, ti3); ins4(c3h.y, base + 65, tv3, ti3);
    ins4(c3h.z, base + 66, tv3, ti3); ins4(c3h.w, base + 67, tv3, ti3);
  }

  // merge 16 per-thread lists per query row via LDS (reuse staging buffers)
  __syncthreads();
  float* mv = (float*)(void*)&As[0][0][0];  // 64*16*4 = 4096 floats <= 4352
  int*   mi = (int*)(void*)&Bs[0][0][0];    // <= 8448
  {
    int o0 = ((ty * 4 + 0) * 16 + tx) * 4;
    mv[o0+0] = tv0.x; mv[o0+1] = tv0.y; mv[o0+2] = tv0.z; mv[o0+3] = tv0.w;
    mi[o0+0] = ti0.x; mi[o0+1] = ti0.y; mi[o0+2] = ti0.z; mi[o0+3] = ti0.w;
    int o1 = ((ty * 4 + 1) * 16 + tx) * 4;
    mv[o1+0] = tv1.x; mv[o1+1] = tv1.y; mv[o1+2] = tv1.z; mv[o1+3] = tv1.w;
    mi[o1+0] = ti1.x; mi[o1+1] = ti1.y; mi[o1+2] = ti1.z; mi[o1+3] = ti1.w;
    int o2 = ((ty * 4 + 2) * 16 + tx) * 4;
    mv[o2+0] = tv2.x; mv[o2+1] = tv2.y; mv[o2+2] = tv2.z; mv[o2+3] = tv2.w;
    mi[o2+0] = ti2.x; mi[o2+1] = ti2.y; mi[o2+2] = ti2.z; mi[o2+3] = ti2.w;
    int o3 = ((ty * 4 + 3) * 16 + tx) * 4;
    mv[o3+0] = tv3.x; mv[o3+1] = tv3.y; mv[o3+2] = tv3.z; mv[o3+3] = tv3.w;
    mi[o3+0] = ti3.x; mi[o3+1] = ti3.y; mi[o3+2] = ti3.z; mi[o3+3] = ti3.w;
  }
  __syncthreads();
  if (tid < BM) {
    float4 bv = NEGI;
    int4   bi = MAXI;
#pragma unroll 1
    for (int c = 0; c < 16; ++c) {
      const int o = (tid * 16 + c) * 4;
      ins4_tb(mv[o+0], mi[o+0], bv, bi);
      ins4_tb(mv[o+1], mi[o+1], bv, bi);
      ins4_tb(mv[o+2], mi[o+2], bv, bi);
      ins4_tb(mv[o+3], mi[o+3], bv, bi);
    }
    const int q = mgrp * BM + tid;
    const size_t o = ((size_t)q * NCHUNK + chnk) * 4;
    cv[o+0] = bv.x; cv[o+1] = bv.y; cv[o+2] = bv.z; cv[o+3] = bv.w;
    ci[o+0] = bi.x; ci[o+1] = bi.y; ci[o+2] = bi.z; ci[o+3] = bi.w;
  }
}

// ---------- kernel B: merge 4 chunks/level -> final top-4, emit sampling_locations ----------
__global__ void merge_loc(const float* __restrict__ cv, const int* __restrict__ ci,
                          int* __restrict__ tix, float* __restrict__ sloc)
{
  const int g = blockIdx.x * 256 + threadIdx.x;
  if (g >= LQ * NLVL) return;
  const int q = g >> 2, l = g & 3;
  float bv[4] = {-3.4e38f, -3.4e38f, -3.4e38f, -3.4e38f};
  int   bi[4] = {0x7fffffff, 0x7fffffff, 0x7fffffff, 0x7fffffff};
#pragma unroll
  for (int c = 0; c < 4; ++c) {
    const int ch = l * 4 + c;
#pragma unroll
    for (int s = 0; s < 4; ++s)
      ins_tb(cv[((size_t)q * NCHUNK + ch) * 4 + s],
             ci[((size_t)q * NCHUNK + ch) * 4 + s], bv, bi);
  }
  const int nei[9] = {-65, -64, -63, -1, 0, 1, 63, 64, 65};
  float* sl = sloc + (size_t)g * 72;   // 36 points * 2
#pragma unroll
  for (int p = 0; p < 4; ++p) {
    const int li = bi[p] - l * LVLN;   // level-local index in [0,4096)
    tix[g * 4 + p] = li;
#pragma unroll
    for (int n9 = 0; n9 < 9; ++n9) {
      int r = li + nei[n9];
      r = r < 0 ? 0 : (r > CLIPMX ? CLIPMX : r);
      // j = n9*4 + p ; loc = (off_w/64, off_h/64), exact
      sl[(n9 * 4 + p) * 2 + 0] = (float)(r >> 6) * 0.015625f;
      sl[(n9 * 4 + p) * 2 + 1] = (float)(r & 63) * 0.015625f;
    }
  }
}

// ---------- kernel C: gather + accumulate pre-projection output ----------
// one block per query, one thread per channel
__global__ void samp_acc(const float* __restrict__ V, const int* __restrict__ tix,
                         float* __restrict__ pre)
{
  const int q = blockIdx.x, d = threadIdx.x;
  const int nei[9] = {-65, -64, -63, -1, 0, 1, 63, 64, 65};
  float acc = 0.f;
#pragma unroll 1
  for (int l = 0; l < NLVL; ++l) {
    const float* Vb = V + (size_t)l * LVLN * DM;
    for (int p = 0; p < 4; ++p) {
      const int p0 = tix[(q * NLVL + l) * 4 + p];
      const int xw = p0 >> 6, yh = p0 & 63;
      if (p0 >= 65 && p0 <= 3904 && yh >= 1 && yh <= 62) {
        // fast path: 4x4 window, weights [1,2,2,1] x [1,2,2,1]
#pragma unroll
        for (int a = 0; a < 4; ++a) {
          const int y = yh - 2 + a;
          if (y < 0) continue;
          const float wa = (a == 1 || a == 2) ? 2.f : 1.f;
#pragma unroll
          for (int bb = 0; bb < 4; ++bb) {
            const int x = xw - 2 + bb;
            if (x < 0) continue;
            const float wb = (bb == 1 || bb == 2) ? 2.f : 1.f;
            acc = fmaf(wa * wb, Vb[(size_t)(y * 64 + x) * DM + d], acc);
          }
        }
      } else {
        // exact per-neighbor path with clip + border masks
#pragma unroll
        for (int n9 = 0; n9 < 9; ++n9) {
          int r = p0 + nei[n9];
          r = r < 0 ? 0 : (r > CLIPMX ? CLIPMX : r);
          const int x = r >> 6, y = r & 63;
          const int b0 = y * 64 + x;
          float s = Vb[(size_t)b0 * DM + d];
          if (x > 0) s += Vb[(size_t)(b0 - 1) * DM + d];
          if (y > 0) {
            s += Vb[(size_t)(b0 - 64) * DM + d];
            if (x > 0) s += Vb[(size_t)(b0 - 65) * DM + d];
          }
          acc += s;
        }
      }
    }
  }
  pre[(size_t)q * DM + d] = acc * (0.25f / 144.f);
}

// ---------- kernel D0: transpose out_w (256x256) ----------
__global__ void transp_w(const float* __restrict__ W, float* __restrict__ Wt)
{
  __shared__ float t[32][33];
  const int bx = blockIdx.x * 32, by = blockIdx.y * 32;
  t[threadIdx.y][threadIdx.x] = W[(size_t)(by + threadIdx.y) * DM + bx + threadIdx.x];
  __syncthreads();
  Wt[(size_t)(bx + threadIdx.y) * DM + by + threadIdx.x] = t[threadIdx.x][threadIdx.y];
}

// ---------- kernel D: out = pre @ W^T + b ----------
__global__ __launch_bounds__(256) void proj_out(
    const float* __restrict__ pre, const float* __restrict__ Wt,
    const float* __restrict__ bias, float* __restrict__ outp)
{
  const int q0 = blockIdx.x * QB;
  const int e = threadIdx.x;
  float acc[QB];
#pragma unroll
  for (int i = 0; i < QB; ++i) acc[i] = 0.f;
#pragma unroll 4
  for (int d = 0; d < DM; ++d) {
    const float w = Wt[(size_t)d * DM + e];   // coalesced, L2-hot
#pragma unroll
    for (int qq = 0; qq < QB; ++qq)
      acc[qq] = fmaf(pre[(size_t)(q0 + qq) * DM + d], w, acc[qq]);  // uniform -> scalar loads
  }
  const float be = bias[e];
#pragma unroll
  for (int qq = 0; qq < QB; ++qq)
    outp[(size_t)(q0 + qq) * DM + e] = acc[qq] + be;
}

extern "C" void kernel_launch(void* const* d_in, const int* in_sizes, int n_in,
                              void* d_out, int out_size, void* d_ws, size_t ws_size,
                              hipStream_t stream)
{
  const float* Q    = (const float*)d_in[0];   // [2048][256]
  const float* V    = (const float*)d_in[2];   // [16384][256]
  const float* W    = (const float*)d_in[5];   // [256][256]
  const float* bias = (const float*)d_in[6];   // [256]

  float* outp = (float*)d_out;                 // [2048][256]
  float* sloc = outp + (size_t)LQ * DM;        // [2048][4][36][2]

  char* ws = (char*)d_ws;
  float* cv  = (float*)(ws);                   // [2048][16][4]  512KB
  int*   ci  = (int*)  (ws + 0x80000);         // [2048][16][4]  512KB
  int*   tix = (int*)  (ws + 0x100000);        // [2048][4][4]   128KB
  float* pre = (float*)(ws + 0x120000);        // [2048][256]    2MB
  float* Wt  = (float*)(ws + 0x320000);        // [256][256]     256KB

  corr_topk<<<dim3(MGRPS, NCHUNK), 256, 0, stream>>>(Q, V, cv, ci);
  merge_loc<<<dim3((LQ * NLVL + 255) / 256), 256, 0, stream>>>(cv, ci, tix, sloc);
  samp_acc<<<dim3(LQ), 256, 0, stream>>>(V, tix, pre);
  transp_w<<<dim3(8, 8), dim3(32, 32), 0, stream>>>(W, Wt);
  proj_out<<<dim3(LQ / QB), 256, 0, stream>>>(pre, Wt, bias, outp);
}

// Round 3
// 502.062 us; speedup vs baseline: 5.5756x; 4.7102x over previous
//
#include <hip/hip_runtime.h>
#include <cstdint>
#include <cstddef>

#define LQ     2048
#define DM     256
#define NKEY   16384
#define NLVL   4
#define LVLN   4096
#define NCHUNK 16
#define CHUNKN 1024
#define BM     64
#define BN     128
#define KB     32
#define MGRPS  (LQ / BM)    // 32
#define CLIPMX 3969         // (h-1)*(w-1)
#define QB     8

// ---------- branchless sorted-insert into top-4, register-only ----------
// strict: later-inserted equal values lose (valid when idx inserted ascending)
__device__ __forceinline__ void ins4(float v, int ix, float4& tv, int4& ti) {
  bool c0 = v > tv.x, c1 = v > tv.y, c2 = v > tv.z, c3 = v > tv.w;
  tv.w = c2 ? tv.z : (c3 ? v : tv.w);
  ti.w = c2 ? ti.z : (c3 ? ix : ti.w);
  tv.z = c1 ? tv.y : (c2 ? v : tv.z);
  ti.z = c1 ? ti.y : (c2 ? ix : ti.z);
  tv.y = c0 ? tv.x : (c1 ? v : tv.y);
  ti.y = c0 ? ti.x : (c1 ? ix : ti.y);
  tv.x = c0 ? v : tv.x;
  ti.x = c0 ? ix : ti.x;
}

// tie-break: equal value -> smaller index wins (numpy/jax top_k semantics)
__device__ __forceinline__ void ins4_tb(float v, int ix, float4& tv, int4& ti) {
  bool c0 = (v > tv.x) || (v == tv.x && ix < ti.x);
  bool c1 = (v > tv.y) || (v == tv.y && ix < ti.y);
  bool c2 = (v > tv.z) || (v == tv.z && ix < ti.z);
  bool c3 = (v > tv.w) || (v == tv.w && ix < ti.w);
  tv.w = c2 ? tv.z : (c3 ? v : tv.w);
  ti.w = c2 ? ti.z : (c3 ? ix : ti.w);
  tv.z = c1 ? tv.y : (c2 ? v : tv.z);
  ti.z = c1 ? ti.y : (c2 ? ix : ti.z);
  tv.y = c0 ? tv.x : (c1 ? v : tv.y);
  ti.y = c0 ? ti.x : (c1 ? ix : ti.y);
  tv.x = c0 ? v : tv.x;
  ti.x = c0 ? ix : ti.x;
}

// array-based tie-break insert (fallback merge_loc kernel only)
__device__ __forceinline__ void ins_tb(float v, int ix, float tv[4], int ti[4]) {
  bool c0 = (v > tv[0]) || (v == tv[0] && ix < ti[0]);
  bool c1 = (v > tv[1]) || (v == tv[1] && ix < ti[1]);
  bool c2 = (v > tv[2]) || (v == tv[2] && ix < ti[2]);
  bool c3 = (v > tv[3]) || (v == tv[3] && ix < ti[3]);
  tv[3] = c2 ? tv[2] : (c3 ? v : tv[3]);
  ti[3] = c2 ? ti[2] : (c3 ? ix : ti[3]);
  tv[2] = c1 ? tv[1] : (c2 ? v : tv[2]);
  ti[2] = c1 ? ti[1] : (c2 ? ix : ti[2]);
  tv[1] = c0 ? tv[0] : (c1 ? v : tv[1]);
  ti[1] = c0 ? ti[0] : (c1 ? ix : ti[1]);
  tv[0] = c0 ? v : tv[0];
  ti[0] = c0 ? ix : ti[0];
}

#define FMA4(accv, s, bv)                  \
  accv.x = fmaf(s, bv.x, accv.x);          \
  accv.y = fmaf(s, bv.y, accv.y);          \
  accv.z = fmaf(s, bv.z, accv.z);          \
  accv.w = fmaf(s, bv.w, accv.w);

// staging macros shared by gemm_qk and fallback corr_topk (rely on local names)
#define GLOAD(ko)                                                          \
    aR0 = *(const float4*)(Aslab + (size_t)(r0)      * DM + (ko) + s0*4);  \
    aR1 = *(const float4*)(Aslab + (size_t)(r0 + 32) * DM + (ko) + s0*4);  \
    bR0 = *(const float4*)(Bt    + (size_t)(r0)      * DM + (ko) + s0*4);  \
    bR1 = *(const float4*)(Bt    + (size_t)(r0 + 32) * DM + (ko) + s0*4);  \
    bR2 = *(const float4*)(Bt    + (size_t)(r0 + 64) * DM + (ko) + s0*4);  \
    bR3 = *(const float4*)(Bt    + (size_t)(r0 + 96) * DM + (ko) + s0*4);

#define LSTORE(nb)                                                                   \
    As[nb][s0*4+0][r0]    = aR0.x; As[nb][s0*4+1][r0]    = aR0.y;                    \
    As[nb][s0*4+2][r0]    = aR0.z; As[nb][s0*4+3][r0]    = aR0.w;                    \
    As[nb][s0*4+0][r0+32] = aR1.x; As[nb][s0*4+1][r0+32] = aR1.y;                    \
    As[nb][s0*4+2][r0+32] = aR1.z; As[nb][s0*4+3][r0+32] = aR1.w;                    \
    Bs[nb][s0*4+0][r0]    = bR0.x; Bs[nb][s0*4+1][r0]    = bR0.y;                    \
    Bs[nb][s0*4+2][r0]    = bR0.z; Bs[nb][s0*4+3][r0]    = bR0.w;                    \
    Bs[nb][s0*4+0][r0+32] = bR1.x; Bs[nb][s0*4+1][r0+32] = bR1.y;                    \
    Bs[nb][s0*4+2][r0+32] = bR1.z; Bs[nb][s0*4+3][r0+32] = bR1.w;                    \
    Bs[nb][s0*4+0][r0+64] = bR2.x; Bs[nb][s0*4+1][r0+64] = bR2.y;                    \
    Bs[nb][s0*4+2][r0+64] = bR2.z; Bs[nb][s0*4+3][r0+64] = bR2.w;                    \
    Bs[nb][s0*4+0][r0+96] = bR3.x; Bs[nb][s0*4+1][r0+96] = bR3.y;                    \
    Bs[nb][s0*4+2][r0+96] = bR3.z; Bs[nb][s0*4+3][r0+96] = bR3.w;

// ---------- kernel A (fast path): pure fp32 GEMM, one level ----------
// grid (32, 32): 64-row block x 128-col block. C is [2048][4096] level-local.
__global__ __launch_bounds__(256, 1) void gemm_qk(
    const float* __restrict__ Qm, const float* __restrict__ Kb,
    float* __restrict__ C)
{
  const int tid  = threadIdx.x;
  const int mgrp = blockIdx.x;
  const int nb2  = blockIdx.y;
  const int ty = tid >> 4, tx = tid & 15;
  const int r0 = tid >> 3, s0 = tid & 7;

  __shared__ __align__(16) float As[2][KB][BM + 4];
  __shared__ __align__(16) float Bs[2][KB][BN + 4];

  const float* Aslab = Qm + (size_t)mgrp * BM * DM;
  const float* Bt    = Kb + (size_t)nb2 * BN * DM;

  float4 c0l = {0,0,0,0}, c0h = {0,0,0,0};
  float4 c1l = {0,0,0,0}, c1h = {0,0,0,0};
  float4 c2l = {0,0,0,0}, c2h = {0,0,0,0};
  float4 c3l = {0,0,0,0}, c3h = {0,0,0,0};

  float4 aR0, aR1, bR0, bR1, bR2, bR3;

  GLOAD(0)
  LSTORE(0)

#pragma unroll 1
  for (int kc = 0; kc < DM / KB; ++kc) {
    __syncthreads();
    if (kc < DM / KB - 1) {
      GLOAD((kc + 1) * KB)
    }
    const int buf = kc & 1;
#pragma unroll
    for (int k = 0; k < KB; ++k) {
      const float4 av = *(const float4*)&As[buf][k][ty * 4];
      const float4 b0 = *(const float4*)&Bs[buf][k][tx * 4];
      const float4 b1 = *(const float4*)&Bs[buf][k][64 + tx * 4];
      FMA4(c0l, av.x, b0) FMA4(c0h, av.x, b1)
      FMA4(c1l, av.y, b0) FMA4(c1h, av.y, b1)
      FMA4(c2l, av.z, b0) FMA4(c2h, av.z, b1)
      FMA4(c3l, av.w, b0) FMA4(c3h, av.w, b1)
    }
    if (kc < DM / KB - 1) {
      LSTORE((kc & 1) ^ 1)
    }
  }

  float* Cp = C + (size_t)(mgrp * BM + ty * 4) * LVLN + nb2 * BN + tx * 4;
  *(float4*)(Cp + 0 * LVLN)      = c0l;  *(float4*)(Cp + 0 * LVLN + 64) = c0h;
  *(float4*)(Cp + 1 * LVLN)      = c1l;  *(float4*)(Cp + 1 * LVLN + 64) = c1h;
  *(float4*)(Cp + 2 * LVLN)      = c2l;  *(float4*)(Cp + 2 * LVLN + 64) = c2h;
  *(float4*)(Cp + 3 * LVLN)      = c3l;  *(float4*)(Cp + 3 * LVLN + 64) = c3h;
}

// ---------- kernel B (fast path): per-(q,level) top-4 + emit tix/sloc ----------
// one wave per q-row; grid 512 x 256 threads (4 waves/block), per level.
__global__ __launch_bounds__(256) void topk_loc(
    const float* __restrict__ C, const int lvl,
    int* __restrict__ tix, float* __restrict__ sloc)
{
  const int wid  = threadIdx.x >> 6;
  const int lane = threadIdx.x & 63;
  const int q = blockIdx.x * 4 + wid;
  const float* row = C + (size_t)q * LVLN;

  const float4 NEGI = {-3.4e38f, -3.4e38f, -3.4e38f, -3.4e38f};
  const int4   MAXI = {0x7fffffff, 0x7fffffff, 0x7fffffff, 0x7fffffff};
  float4 tv = NEGI;
  int4   ti = MAXI;

#pragma unroll
  for (int it = 0; it < 16; ++it) {
    const int col = it * 256 + lane * 4;
    const float4 v = *(const float4*)(row + col);
    ins4(v.x, col + 0, tv, ti);
    ins4(v.y, col + 1, tv, ti);
    ins4(v.z, col + 2, tv, ti);
    ins4(v.w, col + 3, tv, ti);
  }
  // butterfly merge across 64 lanes (tie-break: value desc, index asc)
#pragma unroll
  for (int d = 1; d < 64; d <<= 1) {
    const float ovx = __shfl_xor(tv.x, d), ovy = __shfl_xor(tv.y, d),
                ovz = __shfl_xor(tv.z, d), ovw = __shfl_xor(tv.w, d);
    const int   oix = __shfl_xor(ti.x, d), oiy = __shfl_xor(ti.y, d),
                oiz = __shfl_xor(ti.z, d), oiw = __shfl_xor(ti.w, d);
    ins4_tb(ovx, oix, tv, ti);
    ins4_tb(ovy, oiy, tv, ti);
    ins4_tb(ovz, oiz, tv, ti);
    ins4_tb(ovw, oiw, tv, ti);
  }

  const int g = q * NLVL + lvl;
  if (lane < 4) {
    const int li = lane == 0 ? ti.x : (lane == 1 ? ti.y : (lane == 2 ? ti.z : ti.w));
    tix[g * 4 + lane] = li;
  }
  if (lane < 36) {
    const int p  = lane & 3, n9 = lane >> 2;
    const int li = p == 0 ? ti.x : (p == 1 ? ti.y : (p == 2 ? ti.z : ti.w));
    const int dy = n9 / 3 - 1, dx = n9 % 3 - 1;
    int r = li + dy * 64 + dx;
    r = r < 0 ? 0 : (r > CLIPMX ? CLIPMX : r);
    sloc[(size_t)g * 72 + lane * 2 + 0] = (float)(r >> 6) * 0.015625f;
    sloc[(size_t)g * 72 + lane * 2 + 1] = (float)(r & 63) * 0.015625f;
  }
}

// ---------- FALLBACK path (round-1 kernels, used only if ws too small) ----------
__global__ __launch_bounds__(256, 2) void corr_topk(
    const float* __restrict__ Qm, const float* __restrict__ Km,
    float* __restrict__ cv, int* __restrict__ ci)
{
  const int tid  = threadIdx.x;
  const int mgrp = blockIdx.x;
  const int chnk = blockIdx.y;
  const int ty = tid >> 4, tx = tid & 15;
  const int r0 = tid >> 3, s0 = tid & 7;

  __shared__ __align__(16) float As[2][KB][BM + 4];
  __shared__ __align__(16) float Bs[2][KB][BN + 4];

  const float4 NEGI = {-3.4e38f, -3.4e38f, -3.4e38f, -3.4e38f};
  const int4   MAXI = {0x7fffffff, 0x7fffffff, 0x7fffffff, 0x7fffffff};
  float4 tv0 = NEGI, tv1 = NEGI, tv2 = NEGI, tv3 = NEGI;
  int4   ti0 = MAXI, ti1 = MAXI, ti2 = MAXI, ti3 = MAXI;

  const float* Aslab = Qm + (size_t)mgrp * BM * DM;
  const float* Bslab = Km + (size_t)chnk * CHUNKN * DM;

#pragma unroll 1
  for (int nt = 0; nt < CHUNKN / BN; ++nt) {
    const float* Bt = Bslab + (size_t)nt * BN * DM;

    float4 c0l = {0,0,0,0}, c0h = {0,0,0,0};
    float4 c1l = {0,0,0,0}, c1h = {0,0,0,0};
    float4 c2l = {0,0,0,0}, c2h = {0,0,0,0};
    float4 c3l = {0,0,0,0}, c3h = {0,0,0,0};

    float4 aR0, aR1, bR0, bR1, bR2, bR3;

    GLOAD(0)
    LSTORE(0)

#pragma unroll 1
    for (int kc = 0; kc < DM / KB; ++kc) {
      __syncthreads();
      if (kc < DM / KB - 1) {
        GLOAD((kc + 1) * KB)
      }
      const int buf = kc & 1;
#pragma unroll
      for (int k = 0; k < KB; ++k) {
        const float4 av = *(const float4*)&As[buf][k][ty * 4];
        const float4 b0 = *(const float4*)&Bs[buf][k][tx * 4];
        const float4 b1 = *(const float4*)&Bs[buf][k][64 + tx * 4];
        FMA4(c0l, av.x, b0) FMA4(c0h, av.x, b1)
        FMA4(c1l, av.y, b0) FMA4(c1h, av.y, b1)
        FMA4(c2l, av.z, b0) FMA4(c2h, av.z, b1)
        FMA4(c3l, av.w, b0) FMA4(c3h, av.w, b1)
      }
      if (kc < DM / KB - 1) {
        LSTORE((kc & 1) ^ 1)
      }
    }

    const int base = chnk * CHUNKN + nt * BN + tx * 4;
    ins4(c0l.x, base + 0, tv0, ti0); ins4(c0l.y, base + 1, tv0, ti0);
    ins4(c0l.z, base + 2, tv0, ti0); ins4(c0l.w, base + 3, tv0, ti0);
    ins4(c0h.x, base + 64, tv0, ti0); ins4(c0h.y, base + 65, tv0, ti0);
    ins4(c0h.z, base + 66, tv0, ti0); ins4(c0h.w, base + 67, tv0, ti0);

    ins4(c1l.x, base + 0, tv1, ti1); ins4(c1l.y, base + 1, tv1, ti1);
    ins4(c1l.z, base + 2, tv1, ti1); ins4(c1l.w, base + 3, tv1, ti1);
    ins4(c1h.x, base + 64, tv1, ti1); ins4(c1h.y, base + 65, tv1, ti1);
    ins4(c1h.z, base + 66, tv1, ti1); ins4(c1h.w, base + 67, tv1, ti1);

    ins4(c2l.x, base + 0, tv2, ti2); ins4(c2l.y, base + 1, tv2, ti2);
    ins4(c2l.z, base + 2, tv2, ti2); ins4(c2l.w, base + 3, tv2, ti2);
    ins4(c2h.x, base + 64, tv2, ti2); ins4(c2h.y, base + 65, tv2, ti2);
    ins4(c2h.z, base + 66, tv2, ti2); ins4(c2h.w, base + 67, tv2, ti2);

    ins4(c3l.x, base + 0, tv3, ti3); ins4(c3l.y, base + 1, tv3, ti3);
    ins4(c3l.z, base + 2, tv3, ti3); ins4(c3l.w, base + 3, tv3, ti3);
    ins4(c3h.x, base + 64, tv3, ti3); ins4(c3h.y, base + 65, tv3, ti3);
    ins4(c3h.z, base + 66, tv3, ti3); ins4(c3h.w, base + 67, tv3, ti3);
  }

  __syncthreads();
  float* mv = (float*)(void*)&As[0][0][0];
  int*   mi = (int*)(void*)&Bs[0][0][0];
  {
    int o0 = ((ty * 4 + 0) * 16 + tx) * 4;
    mv[o0+0] = tv0.x; mv[o0+1] = tv0.y; mv[o0+2] = tv0.z; mv[o0+3] = tv0.w;
    mi[o0+0] = ti0.x; mi[o0+1] = ti0.y; mi[o0+2] = ti0.z; mi[o0+3] = ti0.w;
    int o1 = ((ty * 4 + 1) * 16 + tx) * 4;
    mv[o1+0] = tv1.x; mv[o1+1] = tv1.y; mv[o1+2] = tv1.z; mv[o1+3] = tv1.w;
    mi[o1+0] = ti1.x; mi[o1+1] = ti1.y; mi[o1+2] = ti1.z; mi[o1+3] = ti1.w;
    int o2 = ((ty * 4 + 2) * 16 + tx) * 4;
    mv[o2+0] = tv2.x; mv[o2+1] = tv2.y; mv[o2+2] = tv2.z; mv[o2+3] = tv2.w;
    mi[o2+0] = ti2.x; mi[o2+1] = ti2.y; mi[o2+2] = ti2.z; mi[o2+3] = ti2.w;
    int o3 = ((ty * 4 + 3) * 16 + tx) * 4;
    mv[o3+0] = tv3.x; mv[o3+1] = tv3.y; mv[o3+2] = tv3.z; mv[o3+3] = tv3.w;
    mi[o3+0] = ti3.x; mi[o3+1] = ti3.y; mi[o3+2] = ti3.z; mi[o3+3] = ti3.w;
  }
  __syncthreads();
  if (tid < BM) {
    float4 bv = NEGI;
    int4   bi = MAXI;
#pragma unroll 1
    for (int c = 0; c < 16; ++c) {
      const int o = (tid * 16 + c) * 4;
      ins4_tb(mv[o+0], mi[o+0], bv, bi);
      ins4_tb(mv[o+1], mi[o+1], bv, bi);
      ins4_tb(mv[o+2], mi[o+2], bv, bi);
      ins4_tb(mv[o+3], mi[o+3], bv, bi);
    }
    const int q = mgrp * BM + tid;
    const size_t o = ((size_t)q * NCHUNK + chnk) * 4;
    cv[o+0] = bv.x; cv[o+1] = bv.y; cv[o+2] = bv.z; cv[o+3] = bv.w;
    ci[o+0] = bi.x; ci[o+1] = bi.y; ci[o+2] = bi.z; ci[o+3] = bi.w;
  }
}

__global__ void merge_loc(const float* __restrict__ cv, const int* __restrict__ ci,
                          int* __restrict__ tix, float* __restrict__ sloc)
{
  const int g = blockIdx.x * 256 + threadIdx.x;
  if (g >= LQ * NLVL) return;
  const int q = g >> 2, l = g & 3;
  float bv[4] = {-3.4e38f, -3.4e38f, -3.4e38f, -3.4e38f};
  int   bi[4] = {0x7fffffff, 0x7fffffff, 0x7fffffff, 0x7fffffff};
#pragma unroll
  for (int c = 0; c < 4; ++c) {
    const int ch = l * 4 + c;
#pragma unroll
    for (int s = 0; s < 4; ++s)
      ins_tb(cv[((size_t)q * NCHUNK + ch) * 4 + s],
             ci[((size_t)q * NCHUNK + ch) * 4 + s], bv, bi);
  }
  const int nei[9] = {-65, -64, -63, -1, 0, 1, 63, 64, 65};
  float* sl = sloc + (size_t)g * 72;
#pragma unroll
  for (int p = 0; p < 4; ++p) {
    const int li = bi[p] - l * LVLN;
    tix[g * 4 + p] = li;
#pragma unroll
    for (int n9 = 0; n9 < 9; ++n9) {
      int r = li + nei[n9];
      r = r < 0 ? 0 : (r > CLIPMX ? CLIPMX : r);
      sl[(n9 * 4 + p) * 2 + 0] = (float)(r >> 6) * 0.015625f;
      sl[(n9 * 4 + p) * 2 + 1] = (float)(r & 63) * 0.015625f;
    }
  }
}

// ---------- kernel C: gather + accumulate pre-projection output ----------
__global__ void samp_acc(const float* __restrict__ V, const int* __restrict__ tix,
                         float* __restrict__ pre)
{
  const int q = blockIdx.x, d = threadIdx.x;
  const int nei[9] = {-65, -64, -63, -1, 0, 1, 63, 64, 65};
  float acc = 0.f;
#pragma unroll 1
  for (int l = 0; l < NLVL; ++l) {
    const float* Vb = V + (size_t)l * LVLN * DM;
    for (int p = 0; p < 4; ++p) {
      const int p0 = tix[(q * NLVL + l) * 4 + p];
      const int xw = p0 >> 6, yh = p0 & 63;
      if (p0 >= 65 && p0 <= 3904 && yh >= 1 && yh <= 62) {
#pragma unroll
        for (int a = 0; a < 4; ++a) {
          const int y = yh - 2 + a;
          if (y < 0) continue;
          const float wa = (a == 1 || a == 2) ? 2.f : 1.f;
#pragma unroll
          for (int bb = 0; bb < 4; ++bb) {
            const int x = xw - 2 + bb;
            if (x < 0) continue;
            const float wb = (bb == 1 || bb == 2) ? 2.f : 1.f;
            acc = fmaf(wa * wb, Vb[(size_t)(y * 64 + x) * DM + d], acc);
          }
        }
      } else {
#pragma unroll
        for (int n9 = 0; n9 < 9; ++n9) {
          int r = p0 + nei[n9];
          r = r < 0 ? 0 : (r > CLIPMX ? CLIPMX : r);
          const int x = r >> 6, y = r & 63;
          const int b0 = y * 64 + x;
          float s = Vb[(size_t)b0 * DM + d];
          if (x > 0) s += Vb[(size_t)(b0 - 1) * DM + d];
          if (y > 0) {
            s += Vb[(size_t)(b0 - 64) * DM + d];
            if (x > 0) s += Vb[(size_t)(b0 - 65) * DM + d];
          }
          acc += s;
        }
      }
    }
  }
  pre[(size_t)q * DM + d] = acc * (0.25f / 144.f);
}

// ---------- kernel D0: transpose out_w (256x256) ----------
__global__ void transp_w(const float* __restrict__ W, float* __restrict__ Wt)
{
  __shared__ float t[32][33];
  const int bx = blockIdx.x * 32, by = blockIdx.y * 32;
  t[threadIdx.y][threadIdx.x] = W[(size_t)(by + threadIdx.y) * DM + bx + threadIdx.x];
  __syncthreads();
  Wt[(size_t)(bx + threadIdx.y) * DM + by + threadIdx.x] = t[threadIdx.x][threadIdx.y];
}

// ---------- kernel D: out = pre @ W^T + b ----------
__global__ __launch_bounds__(256) void proj_out(
    const float* __restrict__ pre, const float* __restrict__ Wt,
    const float* __restrict__ bias, float* __restrict__ outp)
{
  const int q0 = blockIdx.x * QB;
  const int e = threadIdx.x;
  float acc[QB];
#pragma unroll
  for (int i = 0; i < QB; ++i) acc[i] = 0.f;
#pragma unroll 4
  for (int d = 0; d < DM; ++d) {
    const float w = Wt[(size_t)d * DM + e];
#pragma unroll
    for (int qq = 0; qq < QB; ++qq)
      acc[qq] = fmaf(pre[(size_t)(q0 + qq) * DM + d], w, acc[qq]);
  }
  const float be = bias[e];
#pragma unroll
  for (int qq = 0; qq < QB; ++qq)
    outp[(size_t)(q0 + qq) * DM + e] = acc[qq] + be;
}

extern "C" void kernel_launch(void* const* d_in, const int* in_sizes, int n_in,
                              void* d_out, int out_size, void* d_ws, size_t ws_size,
                              hipStream_t stream)
{
  const float* Q    = (const float*)d_in[0];   // [2048][256]
  const float* V    = (const float*)d_in[2];   // [16384][256]
  const float* W    = (const float*)d_in[5];   // [256][256]
  const float* bias = (const float*)d_in[6];   // [256]

  float* outp = (float*)d_out;                 // [2048][256]
  float* sloc = outp + (size_t)LQ * DM;        // [2048][4][36][2]

  char* ws = (char*)d_ws;

  const size_t CORR_B = (size_t)LQ * LVLN * 4; // 33,554,432
  const size_t NEED   = CORR_B + 131072 + 2097152 + 262144; // ~36.0 MB

  if (ws_size >= NEED) {
    // fast path: split GEMM / top-k, per level
    float* corr = (float*)ws;
    int*   tix  = (int*)  (ws + CORR_B);
    float* pre  = (float*)(ws + CORR_B + 131072);
    float* Wt   = (float*)(ws + CORR_B + 131072 + 2097152);

    for (int l = 0; l < NLVL; ++l) {
      gemm_qk<<<dim3(MGRPS, LVLN / BN), 256, 0, stream>>>(
          Q, V + (size_t)l * LVLN * DM, corr);
      topk_loc<<<dim3(LQ / 4), 256, 0, stream>>>(corr, l, tix, sloc);
    }
    samp_acc<<<dim3(LQ), 256, 0, stream>>>(V, tix, pre);
    transp_w<<<dim3(8, 8), dim3(32, 32), 0, stream>>>(W, Wt);
    proj_out<<<dim3(LQ / QB), 256, 0, stream>>>(pre, Wt, bias, outp);
  } else {
    // fallback: round-1 fused path (slow but known-correct)
    float* cv  = (float*)(ws);
    int*   ci  = (int*)  (ws + 0x80000);
    int*   tix = (int*)  (ws + 0x100000);
    float* pre = (float*)(ws + 0x120000);
    float* Wt  = (float*)(ws + 0x320000);

    corr_topk<<<dim3(MGRPS, NCHUNK), 256, 0, stream>>>(Q, V, cv, ci);
    merge_loc<<<dim3((LQ * NLVL + 255) / 256), 256, 0, stream>>>(cv, ci, tix, sloc);
    samp_acc<<<dim3(LQ), 256, 0, stream>>>(V, tix, pre);
    transp_w<<<dim3(8, 8), dim3(32, 32), 0, stream>>>(W, Wt);
    proj_out<<<dim3(LQ / QB), 256, 0, stream>>>(pre, Wt, bias, outp);
  }
}